// Round 10
// baseline (585.781 us; speedup 1.0000x reference)
//
#include <hip/hip_runtime.h>

typedef unsigned short u16;
typedef __attribute__((ext_vector_type(8))) short bf16x8;
typedef __attribute__((ext_vector_type(4))) float f32x4;

__device__ __forceinline__ u16 f2b(float f) {
  union { float f; unsigned u; } c; c.f = f;
  unsigned u = c.u + 0x7fffu + ((c.u >> 16) & 1u);
  return (u16)(u >> 16);
}
__device__ __forceinline__ float b2f(u16 h) {
  union { unsigned u; float f; } c; c.u = ((unsigned)h) << 16;
  return c.f;
}
__device__ __forceinline__ void g2lds16(const void* g, void* l) {
  __builtin_amdgcn_global_load_lds((const __attribute__((address_space(1))) void*)g,
                                   (__attribute__((address_space(3))) void*)l, 16, 0, 0);
}

// ---------------------------------------------------------------- combined f32->bf16
__global__ __launch_bounds__(256)
void cvt_all(const float* __restrict__ x, const float* __restrict__ W_in,
             const float* __restrict__ W_out, const float* __restrict__ W_in_t,
             const float* __restrict__ W_out_t, const float* __restrict__ alpha,
             u16* __restrict__ xb, u16* __restrict__ wib, u16* __restrict__ wob,
             u16* __restrict__ witb, u16* __restrict__ wotb) {
  int i = blockIdx.x * 256 + threadIdx.x;
  const float* src; u16* dst; int j; float sc = 1.f;
  if (i < 4816896)       { src = x;       dst = xb;   j = i; }
  else if ((i -= 4816896) < 442368)  { src = W_in;    dst = wib;  j = i; }
  else if (i < 589824)   { src = W_out;   dst = wob;  j = i - 442368; }
  else if (i < 1032192)  { src = W_in_t;  dst = witb; j = i - 589824; }
  else if (i < 1179648)  { src = W_out_t; dst = wotb; j = i - 1032192; sc = alpha[j / 192]; }
  else return;
  float4 f = ((const float4*)src)[j];
  ushort4 o;
  o.x = f2b(f.x * sc); o.y = f2b(f.y * sc); o.z = f2b(f.z * sc); o.w = f2b(f.w * sc);
  ((ushort4*)dst)[j] = o;
}

// ---------------------------------------------------------------- big GEMM: 256x256, BK=32, deep prefetch
// outb[m,n] = bf16( sum_k A[m,k]*B[n,k] + bias[n] ), K=768 (24 BK-32 tiles).
// MODE 0: single source. MODE 4: dual-dispatch (wg>=nwgA -> secondary
// (Aa2,Bw2,no bias,outb2,N=768,NT=3)); both outputs bf16.
// 8 waves (2M x 4N), per-wave 128x64 out, acc[8][4]; 4-deep LDS rotation
// (4 bufs x (A 16K + B 16K) = 128 KiB, 1 block/CU), prefetch distance 3.
// Ledger: 4 g2lds/thread per tile; steady state vmcnt(12) => tiles t+1..t+3
// in flight (12 loads), tile t landed. Drain 8/4/0 in last 3 iters. Same
// 2-barrier-per-tile discipline as the proven 128^2 loop.
// LDS layout: rows PAIRED into 128-B lines (lrow=row>>1); 16B slot s of line
// lrow holds logical slot s^(lrow&7), slot = (row&1)*4 + kpart. This is the
// proven 0-conflict pattern (2 lanes/bank per 16-lane group).
template<int MODE>
__global__ __launch_bounds__(512, 2)
void gemm256(const u16* __restrict__ Aa, const u16* __restrict__ Bw,
             const u16* __restrict__ Aa2, const u16* __restrict__ Bw2,
             const float* __restrict__ bias,
             u16* __restrict__ outb, u16* __restrict__ outb2,
             int N, int NT, int nwg, int nwgA)
{
  __shared__ u16 S[4][16384];        // buf: A 8192 u16 + B 8192 u16
  constexpr int K = 768;
  constexpr int NKT = 24;
  const int tid = threadIdx.x;
  const int wave = tid >> 6, lane = tid & 63;
  const int r16 = lane & 15, rq = lane >> 4;
  const int wr = wave >> 2, wc = wave & 3;   // 2M x 4N

  const int q8 = nwg >> 3, r8 = nwg & 7;
  const int xcd = blockIdx.x & 7, pos = blockIdx.x >> 3;
  int wg = (xcd < r8 ? xcd * (q8 + 1) : r8 * (q8 + 1) + (xcd - r8) * q8) + pos;

  const u16* Ap = Aa; const u16* Bp = Bw;
  const float* bp = bias;
  u16* ob = outb;
  int Nl = N, NTl = NT;
  if constexpr (MODE == 4) {
    if (wg >= nwgA) {
      Ap = Aa2; Bp = Bw2; bp = nullptr; ob = outb2;
      Nl = 768; NTl = 3; wg -= nwgA;
    }
  }
  const long am0 = (long)(wg / NTl) * 256;
  const long bn0 = (long)(wg % NTl) * 256;

  // staging source offsets: chunk c -> (row, kpart) via inverse swizzle
  auto srcoff = [&](int c) -> long {
    int lrow = c >> 3, slog = (c & 7) ^ (lrow & 7);
    int row = lrow * 2 + (slog >> 2), kp = slog & 3;
    return (long)row * K + kp * 8;
  };
  const u16* a0 = Ap + am0 * K + srcoff(tid);
  const u16* a1 = Ap + am0 * K + srcoff(tid + 512);
  const u16* b0 = Bp + bn0 * K + srcoff(tid);
  const u16* b1 = Bp + bn0 * K + srcoff(tid + 512);

  auto stage = [&](int t) {
    u16* d = S[t & 3];
    const long ko = (long)t * 32;
    g2lds16(a0 + ko, d + tid * 8);
    g2lds16(a1 + ko, d + 4096 + tid * 8);
    g2lds16(b0 + ko, d + 8192 + tid * 8);
    g2lds16(b1 + ko, d + 12288 + tid * 8);
  };

  // per-lane constant read offsets (bytes): frag i at CA + i*1024, j at CB + j*1024
  const int slotc = ((((r16 & 1) << 2) | rq) ^ ((r16 >> 1) & 7)) << 4;
  const int CA = (wr * 64 + (r16 >> 1)) * 128 + slotc;
  const int CB = 16384 + (wc * 32 + (r16 >> 1)) * 128 + slotc;

  f32x4 acc[8][4];
  const f32x4 zero = {0.f, 0.f, 0.f, 0.f};
#pragma unroll
  for (int i = 0; i < 8; ++i)
#pragma unroll
    for (int j = 0; j < 4; ++j) acc[i][j] = zero;

  stage(0); stage(1); stage(2);

#pragma unroll 4
  for (int t = 0; t < NKT; ++t) {
    if (t + 3 < NKT) {
      stage(t + 3);
      asm volatile("s_waitcnt vmcnt(12)" ::: "memory");  // tile t landed; t+1..t+3 in flight
    } else if (t == NKT - 3) {
      asm volatile("s_waitcnt vmcnt(8)" ::: "memory");
    } else if (t == NKT - 2) {
      asm volatile("s_waitcnt vmcnt(4)" ::: "memory");
    } else {
      asm volatile("s_waitcnt vmcnt(0)" ::: "memory");
    }
    __builtin_amdgcn_sched_barrier(0);
    __builtin_amdgcn_s_barrier();
    __builtin_amdgcn_sched_barrier(0);

    const char* base = (const char*)S[t & 3];
    bf16x8 af[8], bfr[4];
#pragma unroll
    for (int i = 0; i < 8; ++i)
      af[i] = *(const bf16x8*)(base + CA + i * 1024);
#pragma unroll
    for (int j = 0; j < 4; ++j)
      bfr[j] = *(const bf16x8*)(base + CB + j * 1024);
#pragma unroll
    for (int i = 0; i < 8; ++i)
#pragma unroll
      for (int j = 0; j < 4; ++j)
        acc[i][j] = __builtin_amdgcn_mfma_f32_16x16x32_bf16(af[i], bfr[j], acc[i][j], 0, 0, 0);

    __builtin_amdgcn_sched_barrier(0);
    __builtin_amdgcn_s_barrier();   // buf (t&3) fully read before iter t+1 stages it
    __builtin_amdgcn_sched_barrier(0);
  }

  // epilogue: D row=(lane>>4)*4+r, col=lane&15
#pragma unroll
  for (int j = 0; j < 4; ++j) {
    int col = (int)bn0 + wc * 64 + j * 16 + r16;
    float bb = bp ? bp[col] : 0.f;
#pragma unroll
    for (int i = 0; i < 8; ++i) {
      long row = am0 + wr * 128 + i * 16 + rq * 4;
#pragma unroll
      for (int r = 0; r < 4; ++r)
        ob[(row + r) * (long)Nl + col] = f2b(acc[i][j][r] + bb);
    }
  }
}

// ---------------------------------------------------------------- final fused GEMM (proven r9 structure)
// out[m,n] = sum_k Aa[m,k]*Bw[n,k] + sum_k Aa2[m,k]*Bw2[n,k] + bias[n]  (f32)
// 128x128 tile, BK=64, 8 waves (4M x 2N), dbuf + vmcnt(4).
__global__ __launch_bounds__(512)
void gemm_fin(const u16* __restrict__ Aa, const u16* __restrict__ Bw,
              const u16* __restrict__ Aa2, const u16* __restrict__ Bw2,
              const float* __restrict__ bias, float* __restrict__ outf,
              int N, int K, int NT, int nwg)
{
  __shared__ u16 As[2][128 * 64];
  __shared__ u16 Bs[2][128 * 64];
  const int tid = threadIdx.x;
  const int wave = tid >> 6, lane = tid & 63;
  const int r16 = lane & 15, rq = lane >> 4;
  const int wr = wave >> 1, wc = wave & 1;

  const int q8 = nwg >> 3, r8 = nwg & 7;
  const int xcd = blockIdx.x & 7, pos = blockIdx.x >> 3;
  int wg = (xcd < r8 ? xcd * (q8 + 1) : r8 * (q8 + 1) + (xcd - r8) * q8) + pos;
  const long am0 = (long)(wg / NT) * 128;
  const long bn0 = (long)(wg % NT) * 128;

  f32x4 acc[2][4];
  const f32x4 zero = {0.f, 0.f, 0.f, 0.f};
#pragma unroll
  for (int i = 0; i < 2; ++i)
#pragma unroll
    for (int j = 0; j < 4; ++j) acc[i][j] = zero;

  const int split = K >> 6;            // 12
  const int nkt = 2 * split;

  auto stage = [&](int kt, int buf) {
    const u16* Asrc = Aa; const u16* Bsrc = Bw; int ko = kt;
    if (kt >= split) { Asrc = Aa2; Bsrc = Bw2; ko = kt - split; }
#pragma unroll
    for (int i = 0; i < 2; ++i) {
      int c = i * 512 + tid;
      int row = c >> 3;
      int lp = (c & 7) ^ (row & 7);
      g2lds16(Asrc + (am0 + row) * (long)K + ko * 64 + lp * 8,
              As[buf] + (i * 512 + wave * 64) * 8);
      g2lds16(Bsrc + (bn0 + row) * (long)K + ko * 64 + lp * 8,
              Bs[buf] + (i * 512 + wave * 64) * 8);
    }
  };

  stage(0, 0);
  for (int kt = 0; kt < nkt; ++kt) {
    const int cur = kt & 1;
    if (kt + 1 < nkt) {
      stage(kt + 1, cur ^ 1);
      asm volatile("s_waitcnt vmcnt(4)" ::: "memory");
    } else {
      asm volatile("s_waitcnt vmcnt(0)" ::: "memory");
    }
    __builtin_amdgcn_sched_barrier(0);
    __builtin_amdgcn_s_barrier();
    __builtin_amdgcn_sched_barrier(0);
#pragma unroll
    for (int kk = 0; kk < 2; ++kk) {
      bf16x8 af[2], bfr[4];
#pragma unroll
      for (int i = 0; i < 2; ++i) {
        int ra = wr * 32 + i * 16 + r16;
        af[i] = *(const bf16x8*)(As[cur] + ((ra * 128 + ((kk * 64 + rq * 16) ^ ((ra & 7) << 4))) >> 1));
      }
#pragma unroll
      for (int j = 0; j < 4; ++j) {
        int rb = wc * 64 + j * 16 + r16;
        bfr[j] = *(const bf16x8*)(Bs[cur] + ((rb * 128 + ((kk * 64 + rq * 16) ^ ((rb & 7) << 4))) >> 1));
      }
#pragma unroll
      for (int i = 0; i < 2; ++i)
#pragma unroll
        for (int j = 0; j < 4; ++j)
          acc[i][j] = __builtin_amdgcn_mfma_f32_16x16x32_bf16(af[i], bfr[j], acc[i][j], 0, 0, 0);
    }
    __builtin_amdgcn_sched_barrier(0);
    __builtin_amdgcn_s_barrier();
    __builtin_amdgcn_sched_barrier(0);
  }

#pragma unroll
  for (int j = 0; j < 4; ++j) {
    int col = (int)bn0 + wc * 64 + j * 16 + r16;
    float bb = bias[col];
#pragma unroll
    for (int i = 0; i < 2; ++i) {
      long row = am0 + wr * 32 + i * 16 + rq * 4;
#pragma unroll
      for (int r = 0; r < 4; ++r)
        outf[(row + r) * (long)N + col] = acc[i][j][r] + bb;
    }
  }
}

// ---------------------------------------------------------------- attention (proven r9)
template<int S, int MODE>
__global__ __launch_bounds__(256)
void attn_k(const u16* __restrict__ qkv, const u16* __restrict__ addin,
            u16* __restrict__ outp,
            const float* __restrict__ rW = nullptr,
            const float* __restrict__ rb_out = nullptr,
            const float* __restrict__ rb_in_t = nullptr,
            const float* __restrict__ rb_out_t = nullptr,
            const float* __restrict__ ralpha = nullptr,
            float* __restrict__ rbc = nullptr, float* __restrict__ rbf = nullptr)
{
  constexpr int NT = (S + 15) / 16;
  constexpr int NB = (NT + 1) / 2;
  __shared__ u16 Ks[224 * 64];
  __shared__ u16 Vt[16384];
  __shared__ u16 Ps[4][2][512];

  const int g = blockIdx.x, h = blockIdx.y;
  const int tid = threadIdx.x;

  if constexpr (MODE == 0) {
    if (g == 128) {                   // biask rider
      int i = h * 256 + tid;
      if (i < 2304) {
        const float4* Wr = (const float4*)(rW + (long)i * 768);
        const float4* br = (const float4*)rb_out;
        float s = 0.f;
#pragma unroll 4
        for (int k = 0; k < 192; ++k) {
          float4 w = Wr[k], b = br[k];
          s += w.x * b.x + w.y * b.y + w.z * b.z + w.w * b.w;
        }
        rbc[i] = s + rb_in_t[i];
      } else {
        int n = i - 2304;
        rbf[n] = rb_out[n] + ralpha[n] * rb_out_t[n];
      }
      return;
    }
  }

  const int wave = tid >> 6, lane = tid & 63;
  const int r16 = lane & 15, rq = lane >> 4;

  int base;
  if constexpr (MODE == 0) base = g * 196;
  else if constexpr (MODE == 1) base = (g / 14) * 3136 + (g % 14);
  else base = (g / 14) * 3136 + (g % 14) * 14;

  auto rowof = [&](int s) -> long {
    if constexpr (MODE == 0) return base + s;
    int t = s / 14, u = s % 14;
    return base + t * 196 + u * (MODE == 1 ? 14 : 1);
  };

#pragma unroll
  for (int i = 0; i < 7; ++i) {
    int c = i * 256 + tid;
    int s = c >> 3, part = c & 7;
    int sc = (s < S) ? s : (S - 1);
    g2lds16(qkv + rowof(sc) * 2304 + 768 + h * 64 + ((part ^ (s & 7)) << 3),
            &Ks[(i * 256 + wave * 64) * 8]);
  }
#pragma unroll
  for (int i = 0; i < 7; ++i) {
    int c = i * 256 + tid;
    int sb, part, slo;
    if (c < 1536) { sb = c >> 9; part = (c >> 6) & 7; slo = c & 63; }
    else { int c2 = c - 1536; sb = 3; part = c2 >> 5; slo = c2 & 31; }
    int s = sb * 64 + slo;
    int sc = (s < S) ? s : (S - 1);
    uint4 v = *(const uint4*)(qkv + rowof(sc) * 2304 + 1536 + h * 64 + part * 8);
    u16* vb = Vt + sb * 4096;
#pragma unroll
    for (int e = 0; e < 4; ++e) {
      unsigned w2 = (&v.x)[e];
      int d0 = part * 8 + 2 * e;
      vb[d0 * 64 + (slo ^ ((2 * e) << 3))]           = (u16)(w2 & 0xffffu);
      vb[(d0 + 1) * 64 + (slo ^ ((2 * e + 1) << 3))] = (u16)(w2 >> 16);
    }
  }
  __syncthreads();

  for (int qt = wave; qt < NT; qt += 4) {
    int q0 = qt * 16;
    int qr = q0 + r16; if (qr > S - 1) qr = S - 1;
    const u16* gq = qkv + rowof(qr) * 2304 + h * 64 + rq * 8;
    bf16x8 aq0 = *(const bf16x8*)(gq);
    bf16x8 aq1 = *(const bf16x8*)(gq + 32);

    float p[4][NT];
#pragma unroll
    for (int kt = 0; kt < NT; ++kt) {
      f32x4 sc4 = {0.f, 0.f, 0.f, 0.f};
      int row = kt * 16 + r16;
      sc4 = __builtin_amdgcn_mfma_f32_16x16x32_bf16(
          aq0, *(const bf16x8*)(Ks + ((row * 128 + ((rq * 16) ^ ((row & 7) << 4))) >> 1)), sc4, 0, 0, 0);
      sc4 = __builtin_amdgcn_mfma_f32_16x16x32_bf16(
          aq1, *(const bf16x8*)(Ks + ((row * 128 + ((64 + rq * 16) ^ ((row & 7) << 4))) >> 1)), sc4, 0, 0, 0);
#pragma unroll
      for (int r = 0; r < 4; ++r) {
        float sv = sc4[r] * 0.18033688011112042f;   // 0.125 * log2(e)
        if (S == 196 && kt == NT - 1) {
          if (kt * 16 + r16 >= S) sv = -1e30f;
        }
        p[r][kt] = sv;
      }
    }

    float rcp[4];
#pragma unroll
    for (int r = 0; r < 4; ++r) {
      float m = p[r][0];
#pragma unroll
      for (int kt = 1; kt < NT; ++kt) m = fmaxf(m, p[r][kt]);
      m = fmaxf(m, __shfl_xor(m, 1));
      m = fmaxf(m, __shfl_xor(m, 2));
      m = fmaxf(m, __shfl_xor(m, 4));
      m = fmaxf(m, __shfl_xor(m, 8));
      float sum = 0.f;
#pragma unroll
      for (int kt = 0; kt < NT; ++kt) {
        float e = exp2f(p[r][kt] - m);
        p[r][kt] = e; sum += e;
      }
      sum += __shfl_xor(sum, 1);
      sum += __shfl_xor(sum, 2);
      sum += __shfl_xor(sum, 4);
      sum += __shfl_xor(sum, 8);
      rcp[r] = 1.f / sum;
    }

    f32x4 oacc[4];
    const f32x4 zero = {0.f, 0.f, 0.f, 0.f};
#pragma unroll
    for (int nt = 0; nt < 4; ++nt) oacc[nt] = zero;

#pragma unroll
    for (int half = 0; half < 2; ++half)
#pragma unroll
      for (int r = 0; r < 4; ++r)
        Ps[wave][0][(rq * 4 + r) * 32 + half * 16 + r16] = f2b(p[r][half]);
    asm volatile("s_waitcnt lgkmcnt(0)" ::: "memory");
    __builtin_amdgcn_sched_barrier(0);

#pragma unroll
    for (int jb = 0; jb < NB; ++jb) {
      u16* Pr = Ps[wave][jb & 1];
      u16* Pw = Ps[wave][(jb & 1) ^ 1];
      bf16x8 ap = *(const bf16x8*)(Pr + r16 * 32 + rq * 8);
      if (jb + 1 < NB) {
#pragma unroll
        for (int half = 0; half < 2; ++half) {
          int kt = (jb + 1) * 2 + half;
#pragma unroll
          for (int r = 0; r < 4; ++r) {
            float pv = (kt < NT) ? p[r][kt] : 0.f;
            Pw[(rq * 4 + r) * 32 + half * 16 + r16] = f2b(pv);
          }
        }
      }
#pragma unroll
      for (int nt = 0; nt < 4; ++nt) {
        bf16x8 bv = *(const bf16x8*)(Vt + (jb >> 1) * 4096 + (nt * 16 + r16) * 64 +
                                     (((jb & 1) * 32 + rq * 8) ^ ((r16 & 7) << 3)));
        oacc[nt] = __builtin_amdgcn_mfma_f32_16x16x32_bf16(ap, bv, oacc[nt], 0, 0, 0);
      }
      if (jb + 1 < NB) {
        asm volatile("s_waitcnt lgkmcnt(0)" ::: "memory");
        __builtin_amdgcn_sched_barrier(0);
      }
    }

#pragma unroll
    for (int r = 0; r < 4; ++r) {
      int q = q0 + rq * 4 + r;
      if (q < S) {
        long orow = rowof(q);
#pragma unroll
        for (int nt = 0; nt < 4; ++nt) {
          float v = oacc[nt][r] * rcp[r];
          long idx = orow * 768 + h * 64 + nt * 16 + r16;
          if constexpr (MODE == 2) v += b2f(addin[idx]);
          outp[idx] = f2b(v);
        }
      }
    }
  }
}

// ---------------------------------------------------------------- launch
extern "C" void kernel_launch(void* const* d_in, const int* in_sizes, int n_in,
                              void* d_out, int out_size, void* d_ws, size_t ws_size,
                              hipStream_t stream)
{
  const float* x       = (const float*)d_in[0];
  const float* W_in    = (const float*)d_in[1];
  const float* b_in    = (const float*)d_in[2];
  const float* W_out   = (const float*)d_in[3];
  const float* b_out   = (const float*)d_in[4];
  const float* W_in_t  = (const float*)d_in[5];
  const float* b_in_t  = (const float*)d_in[6];
  const float* W_out_t = (const float*)d_in[7];
  const float* b_out_t = (const float*)d_in[8];
  const float* alpha   = (const float*)d_in[9];
  float* out = (float*)d_out;

  u16* ws    = (u16*)d_ws;
  u16* wib   = ws;                    // 2304*768
  u16* wob   = wib + 1769472;         // 768*768
  u16* wotb  = wob + 589824;          // 768*768 (alpha-scaled)
  u16* wcb   = wotb + 589824;         // 2304*768  Wc = W_in_t @ W_out
  u16* qkvb  = wcb + 1769472;         // 25088*2304
  u16* reg1  = qkvb + 57802752;       // 25088*768
  u16* reg2  = reg1 + 19267584;       // 25088*768
  u16* witb  = reg2;                  // temp overlay (dead after wc gemm)
  float* bc  = (float*)wib;           // 2304 f32 (overlay after qkv gemm)
  float* bf  = bc + 2304;             // 768 f32

  cvt_all<<<dim3(23424), 256, 0, stream>>>(x, W_in, W_out, W_in_t, W_out_t, alpha,
                                           reg1, wib, wob, witb, wotb);

  // fused: qkv = x @ W_in^T + b_in [882 tiles] + Wc = witb @ wob^T [27 tiles]
  gemm256<4><<<dim3(909), 512, 0, stream>>>(reg1, wib, witb, wob, b_in,
                                            qkvb, wcb, 2304, 9, 909, 882);
  // spatial attention -> a2 (bf16, reg1) + biask rider
  attn_k<196, 0><<<dim3(129, 12), 256, 0, stream>>>(qkvb, nullptr, reg1,
                                                    W_in_t, b_out, b_in_t, b_out_t,
                                                    alpha, bc, bf);
  // xt = a2 @ Wc^T + bc                [25088 x 2304]
  gemm256<0><<<dim3(882), 512, 0, stream>>>(reg1, wcb, nullptr, nullptr, bc,
                                            qkvb, nullptr, 2304, 9, 882, 882);
  // th attention -> reg2; tw attention -> reg2 = tw + th (in place)
  attn_k<224, 1><<<dim3(112, 12), 256, 0, stream>>>(qkvb, nullptr, reg2);
  attn_k<224, 2><<<dim3(112, 12), 256, 0, stream>>>(qkvb, reg2, reg2);
  // out = a2 @ W_out^T + (th+tw) @ (alpha*W_out_t)^T + bf
  gemm_fin<<<dim3(1176), 512, 0, stream>>>(reg1, wob, reg2, wotb, bf,
                                           out, 768, 768, 6, 1176);
}

// Round 11
// 530.134 us; speedup vs baseline: 1.1050x; 1.1050x over previous
//
#include <hip/hip_runtime.h>

typedef unsigned short u16;
typedef __attribute__((ext_vector_type(8))) short bf16x8;
typedef __attribute__((ext_vector_type(4))) float f32x4;

__device__ __forceinline__ u16 f2b(float f) {
  union { float f; unsigned u; } c; c.f = f;
  unsigned u = c.u + 0x7fffu + ((c.u >> 16) & 1u);
  return (u16)(u >> 16);
}
__device__ __forceinline__ float b2f(u16 h) {
  union { unsigned u; float f; } c; c.u = ((unsigned)h) << 16;
  return c.f;
}
__device__ __forceinline__ void g2lds16(const void* g, void* l) {
  __builtin_amdgcn_global_load_lds((const __attribute__((address_space(1))) void*)g,
                                   (__attribute__((address_space(3))) void*)l, 16, 0, 0);
}

// ---------------------------------------------------------------- combined f32->bf16
__global__ __launch_bounds__(256)
void cvt_all(const float* __restrict__ x, const float* __restrict__ W_in,
             const float* __restrict__ W_out, const float* __restrict__ W_in_t,
             const float* __restrict__ W_out_t, const float* __restrict__ alpha,
             u16* __restrict__ xb, u16* __restrict__ wib, u16* __restrict__ wob,
             u16* __restrict__ witb, u16* __restrict__ wotb) {
  int i = blockIdx.x * 256 + threadIdx.x;
  const float* src; u16* dst; int j; float sc = 1.f;
  if (i < 4816896)       { src = x;       dst = xb;   j = i; }
  else if ((i -= 4816896) < 442368)  { src = W_in;    dst = wib;  j = i; }
  else if (i < 589824)   { src = W_out;   dst = wob;  j = i - 442368; }
  else if (i < 1032192)  { src = W_in_t;  dst = witb; j = i - 589824; }
  else if (i < 1179648)  { src = W_out_t; dst = wotb; j = i - 1032192; sc = alpha[j / 192]; }
  else return;
  float4 f = ((const float4*)src)[j];
  ushort4 o;
  o.x = f2b(f.x * sc); o.y = f2b(f.y * sc); o.z = f2b(f.z * sc); o.w = f2b(f.w * sc);
  ((ushort4*)dst)[j] = o;
}

// ---------------------------------------------------------------- GEMM (2-phase dbuf, BK=64, 8 waves — PROVEN r9)
// MODE 0: outb[m,n] = bf16( sum_k Aa[m,k]*Bw[n,k] + bias[n] )
// MODE 3: fused dual-source, 24 k-tiles: kt<12 (Aa,Bw), kt>=12 (Aa2,Bw2);
//         outf = acc + bias (f32).
// MODE 4: dual-dispatch: swizzled wg < nwgA -> primary; else secondary
//         (Aa2,Bw2,no-bias,(u16*)outf, N=768,NT=6), tile wg-nwgA.
// 128x128 tile, BK=64, 8 waves (4M x 2N, 32x64 out each, acc[2][4]);
// global_load_lds staging; dbuf + counted vmcnt(4).
// T2 swizzle (proven 0-conflict): phys 16B part p of row r holds logical p^(r&7).
template<int MODE>
__global__ __launch_bounds__(512)
void gemm_bt(const u16* __restrict__ Aa, const u16* __restrict__ Bw,
             const u16* __restrict__ Aa2, const u16* __restrict__ Bw2,
             const float* __restrict__ bias,
             float* __restrict__ outf, u16* __restrict__ outb,
             int N, int K, int NT, int nwg, int nwgA)
{
  __shared__ u16 As[2][128 * 64];
  __shared__ u16 Bs[2][128 * 64];
  const int tid = threadIdx.x;
  const int wave = tid >> 6, lane = tid & 63;
  const int r16 = lane & 15, rq = lane >> 4;
  const int wr = wave >> 1, wc = wave & 1;   // 4M x 2N wave grid

  const int q8 = nwg >> 3, r8 = nwg & 7;
  const int xcd = blockIdx.x & 7, pos = blockIdx.x >> 3;
  int wg = (xcd < r8 ? xcd * (q8 + 1) : r8 * (q8 + 1) + (xcd - r8) * q8) + pos;

  const u16* Ap = Aa; const u16* Bp = Bw;
  const float* bp = bias;
  u16* ob = outb;
  int Nl = N, NTl = NT;
  if constexpr (MODE == 4) {
    if (wg >= nwgA) {
      Ap = Aa2; Bp = Bw2; bp = nullptr; ob = (u16*)outf;
      Nl = 768; NTl = 6; wg -= nwgA;
    }
  }
  const long am0 = (long)(wg / NTl) * 128;
  const long bn0 = (long)(wg % NTl) * 128;

  f32x4 acc[2][4];
  const f32x4 zero = {0.f, 0.f, 0.f, 0.f};
#pragma unroll
  for (int i = 0; i < 2; ++i)
#pragma unroll
    for (int j = 0; j < 4; ++j) acc[i][j] = zero;

  const int split = K >> 6;                        // 12 for K=768
  const int nkt = (MODE == 3) ? 2 * split : split;

  auto stage = [&](int kt, int buf) {
    const u16* Asrc = Ap; const u16* Bsrc = Bp; int ko = kt;
    if constexpr (MODE == 3) {
      if (kt >= split) { Asrc = Aa2; Bsrc = Bw2; ko = kt - split; }
    }
#pragma unroll
    for (int i = 0; i < 2; ++i) {
      int c = i * 512 + tid;                       // 1024 chunks of 8 bf16
      int row = c >> 3;
      int lp = (c & 7) ^ (row & 7);
      g2lds16(Asrc + (am0 + row) * (long)K + ko * 64 + lp * 8,
              As[buf] + (i * 512 + wave * 64) * 8);
      g2lds16(Bsrc + (bn0 + row) * (long)K + ko * 64 + lp * 8,
              Bs[buf] + (i * 512 + wave * 64) * 8);
    }
  };

  stage(0, 0);
  for (int kt = 0; kt < nkt; ++kt) {
    const int cur = kt & 1;
    if (kt + 1 < nkt) {
      stage(kt + 1, cur ^ 1);
      asm volatile("s_waitcnt vmcnt(4)" ::: "memory");   // tile kt landed; kt+1 in flight
    } else {
      asm volatile("s_waitcnt vmcnt(0)" ::: "memory");
    }
    __builtin_amdgcn_sched_barrier(0);
    __builtin_amdgcn_s_barrier();
    __builtin_amdgcn_sched_barrier(0);
#pragma unroll
    for (int kk = 0; kk < 2; ++kk) {
      bf16x8 af[2], bfr[4];
#pragma unroll
      for (int i = 0; i < 2; ++i) {
        int ra = wr * 32 + i * 16 + r16;
        af[i] = *(const bf16x8*)(As[cur] + ((ra * 128 + ((kk * 64 + rq * 16) ^ ((ra & 7) << 4))) >> 1));
      }
#pragma unroll
      for (int j = 0; j < 4; ++j) {
        int rb = wc * 64 + j * 16 + r16;
        bfr[j] = *(const bf16x8*)(Bs[cur] + ((rb * 128 + ((kk * 64 + rq * 16) ^ ((rb & 7) << 4))) >> 1));
      }
#pragma unroll
      for (int i = 0; i < 2; ++i)
#pragma unroll
        for (int j = 0; j < 4; ++j)
          acc[i][j] = __builtin_amdgcn_mfma_f32_16x16x32_bf16(af[i], bfr[j], acc[i][j], 0, 0, 0);
    }
    __builtin_amdgcn_sched_barrier(0);
    __builtin_amdgcn_s_barrier();   // protect buf cur before stage(kt+2) overwrites
    __builtin_amdgcn_sched_barrier(0);
  }

  // epilogue: D row=(lane>>4)*4+r, col=lane&15
#pragma unroll
  for (int j = 0; j < 4; ++j) {
    int col = (int)bn0 + wc * 64 + j * 16 + r16;
    float bb = bp ? bp[col] : 0.f;
#pragma unroll
    for (int i = 0; i < 2; ++i) {
      long row = am0 + wr * 32 + i * 16 + rq * 4;
#pragma unroll
      for (int r = 0; r < 4; ++r) {
        float v = acc[i][j][r] + bb;
        long idx = (row + r) * (long)Nl + col;
        if constexpr (MODE == 3) outf[idx] = v;
        else                     ob[idx] = f2b(v);
      }
    }
  }
}

// ---------------------------------------------------------------- attention (8 waves / 512 thr)
// One workgroup per (group g, head h). qkv rows via mode mapping:
//   MODE 0 (spatial): row = g*196 + s   [+ biask rider at blockIdx.x==128]
//   MODE 1 (th): g=(b,w): row = b*3136 + w + (s/14)*196 + (s%14)*14
//   MODE 2 (tw): g=(b,h'): row = b*3136 + h'*14 + (s/14)*196 + (s%14)
// Output bf16; MODE 2 adds addin[idx] (may alias outp). Softmax in exp2 domain.
// 8 waves: q-tiles split qt = wave, += 8 -> per-block critical path ~halves,
// 16 waves/CU resident (2 blocks x 8) vs 8 before — latency hiding for the
// softmax VALU chains + gathered Q loads. LDS 77.8 KB -> still 2 blocks/CU.
// Vt layout (conflict-free): u16 idx(d,s) = (s>>6)*4096 + d*64 + ((s&63)^((d&7)<<3)).
// PV: ping-pong P buffers -> ONE lgkmcnt(0) per jb.
template<int S, int MODE>
__global__ __launch_bounds__(512)
void attn_k(const u16* __restrict__ qkv, const u16* __restrict__ addin,
            u16* __restrict__ outp,
            const float* __restrict__ rW = nullptr,
            const float* __restrict__ rb_out = nullptr,
            const float* __restrict__ rb_in_t = nullptr,
            const float* __restrict__ rb_out_t = nullptr,
            const float* __restrict__ ralpha = nullptr,
            float* __restrict__ rbc = nullptr, float* __restrict__ rbf = nullptr)
{
  constexpr int NT = (S + 15) / 16;   // 13 (S=196) or 14 (S=224)
  constexpr int NB = (NT + 1) / 2;    // 7
  __shared__ u16 Ks[224 * 64];        // K rows, 128-B rows, XOR-swizzled (28 KB)
  __shared__ u16 Vt[16384];           // V^T, 4 s-blocks x 64 d-rows x 64 (32 KB)
  __shared__ u16 Ps[8][2][512];       // per-wave ping-pong P scratch (16 KB)

  const int g = blockIdx.x, h = blockIdx.y;
  const int tid = threadIdx.x;

  if constexpr (MODE == 0) {
    if (g == 128) {                   // biask rider: 12 blocks x 512 lanes, 3072 items
      int i = h * 512 + tid;
      if (i < 2304) {
        const float4* Wr = (const float4*)(rW + (long)i * 768);
        const float4* br = (const float4*)rb_out;
        float s = 0.f;
#pragma unroll 4
        for (int k = 0; k < 192; ++k) {
          float4 w = Wr[k], b = br[k];
          s += w.x * b.x + w.y * b.y + w.z * b.z + w.w * b.w;
        }
        rbc[i] = s + rb_in_t[i];
      } else if (i < 3072) {
        int n = i - 2304;
        rbf[n] = rb_out[n] + ralpha[n] * rb_out_t[n];
      }
      return;
    }
  }

  const int wave = tid >> 6, lane = tid & 63;
  const int r16 = lane & 15, rq = lane >> 4;

  int base;
  if constexpr (MODE == 0) base = g * 196;
  else if constexpr (MODE == 1) base = (g / 14) * 3136 + (g % 14);
  else base = (g / 14) * 3136 + (g % 14) * 14;

  auto rowof = [&](int s) -> long {
    if constexpr (MODE == 0) return base + s;
    int t = s / 14, u = s % 14;
    return base + t * 196 + u * (MODE == 1 ? 14 : 1);
  };

  // ---- stage K (1792 chunks; wave-uniform guard, 64-chunk granularity) ----
#pragma unroll
  for (int i = 0; i < 4; ++i) {
    if (i * 512 + wave * 64 < 1792) {
      int c = i * 512 + tid;          // 224 rows x 8 parts
      int s = c >> 3, part = c & 7;
      int sc = (s < S) ? s : (S - 1);
      g2lds16(qkv + rowof(sc) * 2304 + 768 + h * 64 + ((part ^ (s & 7)) << 3),
              &Ks[(i * 512 + wave * 64) * 8]);
    }
  }
  // ---- stage V transposed, s-major lanes, conflict-free writes ----
#pragma unroll
  for (int i = 0; i < 4; ++i) {
    int c = i * 512 + tid;
    if (c < 1792) {
      int sb, part, slo;
      if (c < 1536) { sb = c >> 9; part = (c >> 6) & 7; slo = c & 63; }
      else { int c2 = c - 1536; sb = 3; part = c2 >> 5; slo = c2 & 31; }
      int s = sb * 64 + slo;
      int sc = (s < S) ? s : (S - 1);
      uint4 v = *(const uint4*)(qkv + rowof(sc) * 2304 + 1536 + h * 64 + part * 8);
      u16* vb = Vt + sb * 4096;
#pragma unroll
      for (int e = 0; e < 4; ++e) {
        unsigned w2 = (&v.x)[e];
        int d0 = part * 8 + 2 * e;
        vb[d0 * 64 + (slo ^ ((2 * e) << 3))]           = (u16)(w2 & 0xffffu);
        vb[(d0 + 1) * 64 + (slo ^ ((2 * e + 1) << 3))] = (u16)(w2 >> 16);
      }
    }
  }
  __syncthreads();

  // ---- per-wave q-tiles (16 rows each; 8 waves) ----
  for (int qt = wave; qt < NT; qt += 8) {
    int q0 = qt * 16;
    int qr = q0 + r16; if (qr > S - 1) qr = S - 1;
    const u16* gq = qkv + rowof(qr) * 2304 + h * 64 + rq * 8;
    bf16x8 aq0 = *(const bf16x8*)(gq);
    bf16x8 aq1 = *(const bf16x8*)(gq + 32);

    float p[4][NT];
#pragma unroll
    for (int kt = 0; kt < NT; ++kt) {
      f32x4 sc4 = {0.f, 0.f, 0.f, 0.f};
      int row = kt * 16 + r16;
      sc4 = __builtin_amdgcn_mfma_f32_16x16x32_bf16(
          aq0, *(const bf16x8*)(Ks + ((row * 128 + ((rq * 16) ^ ((row & 7) << 4))) >> 1)), sc4, 0, 0, 0);
      sc4 = __builtin_amdgcn_mfma_f32_16x16x32_bf16(
          aq1, *(const bf16x8*)(Ks + ((row * 128 + ((64 + rq * 16) ^ ((row & 7) << 4))) >> 1)), sc4, 0, 0, 0);
#pragma unroll
      for (int r = 0; r < 4; ++r) {
        float sv = sc4[r] * 0.18033688011112042f;   // 0.125 * log2(e)
        if (S == 196 && kt == NT - 1) {
          if (kt * 16 + r16 >= S) sv = -1e30f;      // mask padded keys
        }
        p[r][kt] = sv;
      }
    }

    // ---- softmax in exp2 domain (rows live in 16-lane groups sharing rq) ----
    float rcp[4];
#pragma unroll
    for (int r = 0; r < 4; ++r) {
      float m = p[r][0];
#pragma unroll
      for (int kt = 1; kt < NT; ++kt) m = fmaxf(m, p[r][kt]);
      m = fmaxf(m, __shfl_xor(m, 1));
      m = fmaxf(m, __shfl_xor(m, 2));
      m = fmaxf(m, __shfl_xor(m, 4));
      m = fmaxf(m, __shfl_xor(m, 8));
      float sum = 0.f;
#pragma unroll
      for (int kt = 0; kt < NT; ++kt) {
        float e = exp2f(p[r][kt] - m);
        p[r][kt] = e; sum += e;
      }
      sum += __shfl_xor(sum, 1);
      sum += __shfl_xor(sum, 2);
      sum += __shfl_xor(sum, 4);
      sum += __shfl_xor(sum, 8);
      rcp[r] = 1.f / sum;
    }

    // ---- PV: ping-pong P, one lgkmcnt per jb ----
    f32x4 oacc[4];
    const f32x4 zero = {0.f, 0.f, 0.f, 0.f};
#pragma unroll
    for (int nt = 0; nt < 4; ++nt) oacc[nt] = zero;

#pragma unroll
    for (int half = 0; half < 2; ++half)
#pragma unroll
      for (int r = 0; r < 4; ++r)
        Ps[wave][0][(rq * 4 + r) * 32 + half * 16 + r16] = f2b(p[r][half]);
    asm volatile("s_waitcnt lgkmcnt(0)" ::: "memory");
    __builtin_amdgcn_sched_barrier(0);

#pragma unroll
    for (int jb = 0; jb < NB; ++jb) {
      u16* Pr = Ps[wave][jb & 1];
      u16* Pw = Ps[wave][(jb & 1) ^ 1];
      bf16x8 ap = *(const bf16x8*)(Pr + r16 * 32 + rq * 8);
      if (jb + 1 < NB) {
#pragma unroll
        for (int half = 0; half < 2; ++half) {
          int kt = (jb + 1) * 2 + half;
#pragma unroll
          for (int r = 0; r < 4; ++r) {
            float pv = (kt < NT) ? p[r][kt] : 0.f;
            Pw[(rq * 4 + r) * 32 + half * 16 + r16] = f2b(pv);
          }
        }
      }
#pragma unroll
      for (int nt = 0; nt < 4; ++nt) {
        bf16x8 bv = *(const bf16x8*)(Vt + (jb >> 1) * 4096 + (nt * 16 + r16) * 64 +
                                     (((jb & 1) * 32 + rq * 8) ^ ((r16 & 7) << 3)));
        oacc[nt] = __builtin_amdgcn_mfma_f32_16x16x32_bf16(ap, bv, oacc[nt], 0, 0, 0);
      }
      if (jb + 1 < NB) {
        asm volatile("s_waitcnt lgkmcnt(0)" ::: "memory");  // Pw writes + Pr read done
        __builtin_amdgcn_sched_barrier(0);
      }
    }

    // ---- write out (bf16); MODE 2 adds th result ----
#pragma unroll
    for (int r = 0; r < 4; ++r) {
      int q = q0 + rq * 4 + r;
      if (q < S) {
        long orow = rowof(q);
#pragma unroll
        for (int nt = 0; nt < 4; ++nt) {
          float v = oacc[nt][r] * rcp[r];
          long idx = orow * 768 + h * 64 + nt * 16 + r16;
          if constexpr (MODE == 2) v += b2f(addin[idx]);
          outp[idx] = f2b(v);
        }
      }
    }
  }
}

// ---------------------------------------------------------------- launch
extern "C" void kernel_launch(void* const* d_in, const int* in_sizes, int n_in,
                              void* d_out, int out_size, void* d_ws, size_t ws_size,
                              hipStream_t stream)
{
  const float* x       = (const float*)d_in[0];
  const float* W_in    = (const float*)d_in[1];
  const float* b_in    = (const float*)d_in[2];
  const float* W_out   = (const float*)d_in[3];
  const float* b_out   = (const float*)d_in[4];
  const float* W_in_t  = (const float*)d_in[5];
  const float* b_in_t  = (const float*)d_in[6];
  const float* W_out_t = (const float*)d_in[7];
  const float* b_out_t = (const float*)d_in[8];
  const float* alpha   = (const float*)d_in[9];
  float* out = (float*)d_out;

  // workspace (u16 units; 202,113,024 bytes total):
  //  wib (bc/bf f32 overlay after qkv gemm) | wob | wotb(alpha-scaled) | wcb |
  //  qkvb | reg1 (xb -> a2) | reg2 (witb overlay -> th -> th+tw)
  u16* ws    = (u16*)d_ws;
  u16* wib   = ws;                    // 2304*768
  u16* wob   = wib + 1769472;         // 768*768
  u16* wotb  = wob + 589824;          // 768*768 (alpha-scaled)
  u16* wcb   = wotb + 589824;         // 2304*768  Wc = W_in_t @ W_out
  u16* qkvb  = wcb + 1769472;         // 25088*2304
  u16* reg1  = qkvb + 57802752;       // 25088*768
  u16* reg2  = reg1 + 19267584;       // 25088*768
  u16* witb  = reg2;                  // temp overlay (dead after wc gemm)
  float* bc  = (float*)wib;           // 2304 f32 (overlay after qkv gemm)
  float* bf  = bc + 2304;             // 768 f32

  cvt_all<<<dim3(23424), 256, 0, stream>>>(x, W_in, W_out, W_in_t, W_out_t, alpha,
                                           reg1, wib, wob, witb, wotb);

  // fused: qkv = x @ W_in^T + b_in  [3528 tiles]  +  Wc = witb @ wob^T  [108 tiles]
  gemm_bt<4><<<dim3(3636), 512, 0, stream>>>(reg1, wib, witb, wob, b_in,
                                             (float*)wcb, qkvb, 2304, 768, 18, 3636, 3528);
  // spatial attention -> a2 (bf16, reg1) + biask rider
  attn_k<196, 0><<<dim3(129, 12), 512, 0, stream>>>(qkvb, nullptr, reg1,
                                                    W_in_t, b_out, b_in_t, b_out_t,
                                                    alpha, bc, bf);
  // xt = a2 @ Wc^T + bc                [25088 x 2304]
  gemm_bt<0><<<dim3(3528), 512, 0, stream>>>(reg1, wcb, nullptr, nullptr, bc,
                                             nullptr, qkvb, 2304, 768, 18, 3528, 0);
  // th attention -> reg2; tw attention -> reg2 = tw + th (in place)
  attn_k<224, 1><<<dim3(112, 12), 512, 0, stream>>>(qkvb, nullptr, reg2);
  attn_k<224, 2><<<dim3(112, 12), 512, 0, stream>>>(qkvb, reg2, reg2);
  // out = a2 @ W_out^T + (th+tw) @ (alpha*W_out_t)^T + bf
  gemm_bt<3><<<dim3(1176), 512, 0, stream>>>(reg1, wob, reg2, wotb, bf,
                                             out, nullptr, 768, 768, 6, 1176, 0);
}